// Round 14
// baseline (188.136 us; speedup 1.0000x reference)
//
#include <hip/hip_runtime.h>

// GraphTransformerBlock2: GATConv(H=3,C=64, edge_dim=5, self-loops w/ mean fill)
// -> linear1 -> LN(x + .) -> linear2 -> LN(lin + .)
// All float32 I/O. edge_index int32 (2,E): src=ei[0:E], dst=ei[E:2E].
//
// R13 (gather-phase lane packing; mean deg = E/N = 16):
//  - 4 nodes per wave: group g=lane>>4 owns a node, eslot=lane&15 its edge slot.
//    Phase A instruction stream serves 4 nodes (was 1 with 48/64 lanes idle);
//    reductions 16-lane x 4 steps for 4 nodes (36 -> 6 ops/node); epilogue
//    scalar math per-group (div4 issue), broadcast via __shfl for the OA write.
//  - OA LDS stride 192 -> 200 u16 (96 dwords === 0 mod 32 was a 16-way bank
//    conflict on GEMM1's A-read: 1.0M SQ_LDS_BANK_CONFLICT in R12).

#define HH 3
#define CC 64
#define DIN 64
#define ED 5
#define HC 192
#define OAP 200                 // padded OA row stride (u16)
#define NEG_SLOPE 0.2f
#define LN_EPS 1e-5f
#define LOG2E 1.44269504f

typedef __attribute__((ext_vector_type(8))) short bf16x8;
typedef __attribute__((ext_vector_type(4))) float f32x4;

__device__ __forceinline__ float leaky(float l) { return fmaxf(l, NEG_SLOPE * l); }

__device__ __forceinline__ unsigned short f2bf(float f) {
    unsigned u = __float_as_uint(f);
    unsigned r = (u + 0x7FFFu + ((u >> 16) & 1u)) >> 16;   // RNE
    return (unsigned short)r;
}
__device__ __forceinline__ float bf2f(unsigned short u) {
    return __uint_as_float((unsigned)u << 16);
}
__device__ __forceinline__ float bf_lo(unsigned v) { return __uint_as_float(v << 16); }
__device__ __forceinline__ float bf_hi(unsigned v) { return __uint_as_float(v & 0xFFFF0000u); }

__device__ __forceinline__ bf16x8 pack8(float4 a, float4 b) {
    bf16x8 r;
    r[0] = (short)f2bf(a.x); r[1] = (short)f2bf(a.y);
    r[2] = (short)f2bf(a.z); r[3] = (short)f2bf(a.w);
    r[4] = (short)f2bf(b.x); r[5] = (short)f2bf(b.y);
    r[6] = (short)f2bf(b.z); r[7] = (short)f2bf(b.w);
    return r;
}

// ---------- prep (bf16 transposed weights + folded bias + we*log2e) + cnt ----------
#define PREP_TOT (HC*DIN + DIN*HC + CC*CC + CC + ED*HH)
#define PREP_BLOCKS 30
__global__ __launch_bounds__(256) void k_prep_cnt(const float* __restrict__ lin_w,
                                                  const float* __restrict__ w1,
                                                  const float* __restrict__ w2,
                                                  const float* __restrict__ b1,
                                                  const float* __restrict__ gat_bias,
                                                  const float* __restrict__ lin_edge_w,
                                                  const float* __restrict__ att_edge,
                                                  unsigned short* __restrict__ linwt,
                                                  unsigned short* __restrict__ w1t,
                                                  unsigned short* __restrict__ w2t,
                                                  float* __restrict__ b1p,
                                                  float* __restrict__ we,
                                                  const int* __restrict__ ei,
                                                  int* __restrict__ icnt, int E) {
    if (blockIdx.x < PREP_BLOCKS) {
        for (int i = blockIdx.x * 256 + threadIdx.x; i < PREP_TOT; i += PREP_BLOCKS * 256) {
            if (i < HC * DIN) {
                int c = i >> 6, k = i & 63;
                linwt[i] = f2bf(lin_w[k * HC + c]);
            } else if (i < 2 * HC * DIN) {
                int j = i - HC * DIN;
                int c = j / HC, k = j - c * HC;
                w1t[j] = f2bf(w1[k * CC + c]);
            } else if (i < 2 * HC * DIN + CC * CC) {
                int j = i - 2 * HC * DIN;
                int c = j >> 6, k = j & 63;
                w2t[j] = f2bf(w2[k * CC + c]);
            } else if (i < 2 * HC * DIN + CC * CC + CC) {
                int c = i - (2 * HC * DIN + CC * CC);
                float s = b1[c];
                for (int k = 0; k < HC; ++k) s += gat_bias[k] * w1[k * CC + c];
                b1p[c] = s;
            } else {
                int q = i - (2 * HC * DIN + CC * CC + CC);
                int d = q / HH, h = q - d * HH;
                float s = 0.f;
                for (int c = 0; c < CC; ++c)
                    s += lin_edge_w[d * HC + h * CC + c] * att_edge[h * CC + c];
                we[q] = s * LOG2E;                     // pre-scale for exp2
            }
        }
    } else {
        int nb = gridDim.x - PREP_BLOCKS;
        for (int e = (blockIdx.x - PREP_BLOCKS) * 256 + threadIdx.x; e < E; e += nb * 256)
            atomicAdd(&icnt[ei[E + e]], 1);
    }
}

// ---------- xs = x @ lin_w (MFMA) -> packed xsb + a_src/a_dst;  scan fused ----------
__global__ __launch_bounds__(256) void k_xs(const float* __restrict__ x,
                                            const unsigned short* __restrict__ linwt,
                                            const float* __restrict__ att_src,
                                            const float* __restrict__ att_dst,
                                            unsigned short* __restrict__ xsb,
                                            float* __restrict__ a_src,
                                            float* __restrict__ a_dst,
                                            const int* __restrict__ icnt,
                                            int* __restrict__ gtot,
                                            int* __restrict__ off,
                                            int* __restrict__ cursor,
                                            int N, int nbx) {
    __shared__ int wt[4];
    __shared__ int base_sh;
    if ((int)blockIdx.x >= nbx) {
        int bid = blockIdx.x - nbx;
        int i = bid * 256 + threadIdx.x;
        int lane = threadIdx.x & 63, wid = threadIdx.x >> 6;
        int v = (i < N) ? icnt[i] : 0;
        int incl = v;
        #pragma unroll
        for (int o = 1; o < 64; o <<= 1) {
            int u = __shfl_up(incl, o, 64);
            if (lane >= o) incl += u;
        }
        if (lane == 63) wt[wid] = incl;
        __syncthreads();
        if (threadIdx.x == 0)
            base_sh = atomicAdd(gtot, wt[0] + wt[1] + wt[2] + wt[3]);
        __syncthreads();
        int wpre = 0;
        for (int w2 = 0; w2 < wid; ++w2) wpre += wt[w2];
        int excl = base_sh + wpre + incl - v;
        if (i < N) { off[i] = excl; cursor[i] = excl; }
        return;
    }

    int lane = threadIdx.x & 63, w = threadIdx.x >> 6;
    int l15 = lane & 15, kg = (lane >> 4) * 8;
    int nb = blockIdx.x * 64;
    int arow = nb + w * 16 + l15;
    int arow_c = min(arow, N - 1);

    f32x4 acc[12];
    #pragma unroll
    for (int ct = 0; ct < 12; ++ct) acc[ct] = (f32x4){0.f, 0.f, 0.f, 0.f};

    #pragma unroll
    for (int k0 = 0; k0 < DIN; k0 += 32) {
        const float* ap = x + (size_t)arow_c * DIN + k0 + kg;
        float4 a0 = *(const float4*)ap;
        float4 a1 = *(const float4*)(ap + 4);
        bf16x8 af = pack8(a0, a1);
        #pragma unroll
        for (int ct = 0; ct < 12; ++ct) {
            bf16x8 bf = *(const bf16x8*)(linwt + (size_t)(ct * 16 + l15) * DIN + k0 + kg);
            acc[ct] = __builtin_amdgcn_mfma_f32_16x16x32_bf16(af, bf, acc[ct], 0, 0, 0);
        }
    }

    float asv[12], adv[12];
    #pragma unroll
    for (int ct = 0; ct < 12; ++ct) {
        int c = ct * 16 + l15;
        asv[ct] = att_src[c]; adv[ct] = att_dst[c];
    }

    int rbase = nb + w * 16 + (lane >> 4) * 4;
    #pragma unroll
    for (int j = 0; j < 4; ++j) {
        int r = rbase + j;
        bool ok = r < N;
        float ps0 = 0.f, ps1 = 0.f, ps2 = 0.f, pd0 = 0.f, pd1 = 0.f, pd2 = 0.f;
        #pragma unroll
        for (int ct = 0; ct < 12; ++ct) {
            float v = acc[ct][j];
            float s = v * asv[ct], d = v * adv[ct];
            if (ct < 4)      { ps0 += s; pd0 += d; }
            else if (ct < 8) { ps1 += s; pd1 += d; }
            else             { ps2 += s; pd2 += d; }
        }
        if (ok) {
            unsigned* row32 = (unsigned*)(xsb + (size_t)r * HC);
            #pragma unroll
            for (int ct = 0; ct < 4; ++ct) {
                int c = ct * 16 + l15;
                row32[c] = (unsigned)f2bf(acc[ct][j]) | ((unsigned)f2bf(acc[ct + 4][j]) << 16);
                xsb[(size_t)r * HC + 128 + c] = f2bf(acc[ct + 8][j]);
            }
        }
        #pragma unroll
        for (int o = 1; o < 16; o <<= 1) {
            ps0 += __shfl_xor(ps0, o, 64); pd0 += __shfl_xor(pd0, o, 64);
            ps1 += __shfl_xor(ps1, o, 64); pd1 += __shfl_xor(pd1, o, 64);
            ps2 += __shfl_xor(ps2, o, 64); pd2 += __shfl_xor(pd2, o, 64);
        }
        if (ok && l15 == 0) {
            a_src[r * HH + 0] = ps0 * LOG2E; a_src[r * HH + 1] = ps1 * LOG2E;
            a_src[r * HH + 2] = ps2 * LOG2E;
            a_dst[r * HH + 0] = pd0 * LOG2E; a_dst[r * HH + 1] = pd1 * LOG2E;
            a_dst[r * HH + 2] = pd2 * LOG2E;
        }
    }
}

// ---------- payload fill (CSR order), 16B/edge, a_dst FOLDED IN ----------
__global__ __launch_bounds__(256) void k_fill(const float* __restrict__ ea,
                                              const int* __restrict__ ei,
                                              const float* __restrict__ a_src,
                                              const float* __restrict__ a_dst,
                                              const float* __restrict__ we,
                                              int* __restrict__ cursor,
                                              uint4* __restrict__ payload, int E) {
    int e = blockIdx.x * blockDim.x + threadIdx.x;
    if (e >= E) return;
    int s = ei[e], d = ei[E + e];
    int pos = atomicAdd(&cursor[d], 1);                  // issue early; hide RMW latency
    float attr[ED];
    #pragma unroll
    for (int j = 0; j < ED; ++j) attr[j] = ea[(size_t)e * ED + j];
    float aeh[HH], lp[HH];
    #pragma unroll
    for (int h = 0; h < HH; ++h) {
        float a = 0.f;
        #pragma unroll
        for (int j = 0; j < ED; ++j) a += attr[j] * we[j * HH + h];   // we pre-scaled
        aeh[h] = a;
        lp[h] = a_src[s * HH + h] + a_dst[d * HH + h] + a;             // all pre-scaled
    }
    uint4 pk;
    pk.x = (unsigned)f2bf(lp[0])  | ((unsigned)f2bf(lp[1])  << 16);
    pk.y = (unsigned)f2bf(lp[2])  | ((unsigned)f2bf(aeh[0]) << 16);
    pk.z = (unsigned)f2bf(aeh[1]) | ((unsigned)f2bf(aeh[2]) << 16);
    pk.w = (unsigned)s;
    payload[pos] = pk;
}

// ---------- FUSED: softmax+gather (4 nodes/wave) -> MLP -> out ----------
__global__ __launch_bounds__(256) void k_gatmlp(const unsigned short* __restrict__ xsb,
                                                const float* __restrict__ a_src,
                                                const float* __restrict__ a_dst,
                                                const int* __restrict__ off,
                                                const int* __restrict__ icnt,
                                                const uint4* __restrict__ payload,
                                                const float* __restrict__ x,
                                                const unsigned short* __restrict__ w1t,
                                                const unsigned short* __restrict__ w2t,
                                                const float* __restrict__ b1p,
                                                const float* __restrict__ g1,
                                                const float* __restrict__ be1,
                                                const float* __restrict__ b2,
                                                const float* __restrict__ g2,
                                                const float* __restrict__ be2,
                                                float* __restrict__ out, int N) {
    __shared__ float4 wbuf[4][64];                 // 4 KB
    __shared__ unsigned short OA[16 * OAP];        // 6.25 KB, padded stride (2-way banks)
    __shared__ unsigned short H1s[16 * 72];        // 2.25 KB
    __shared__ float red[2][4][16];                // 512 B
    int lane = threadIdx.x & 63;
    int wid  = threadIdx.x >> 6;
    const unsigned* xs32 = (const unsigned*)xsb;
    unsigned c128ml = 128u - (unsigned)lane;
    int nb16 = blockIdx.x * 16;

    // ======== gather: group g = lane>>4 owns node wid*4+g ========
    int ngrp = lane >> 4, eslot = lane & 15;
    int n_g = nb16 + wid * 4 + ngrp;
    int n_gc = min(n_g, N - 1);
    int beg_g = off[n_gc];
    int deg_g = (n_g < N) ? icnt[n_g] : 0;

    int maxdeg = deg_g;
    maxdeg = max(maxdeg, __shfl_xor(maxdeg, 16, 64));
    maxdeg = max(maxdeg, __shfl_xor(maxdeg, 32, 64));

    float pden0 = 0.f, pden1 = 0.f, pden2 = 0.f;
    float pae0 = 0.f, pae1 = 0.f, pae2 = 0.f;
    float aA0[4], aA1[4], aA2[4], aB0[4], aB1[4], aB2[4];
    #pragma unroll
    for (int g = 0; g < 4; ++g) {
        aA0[g] = 0.f; aA1[g] = 0.f; aA2[g] = 0.f;
        aB0[g] = 0.f; aB1[g] = 0.f; aB2[g] = 0.f;
    }

    for (int c0 = 0; c0 < maxdeg; c0 += 16) {
        // --- phase A: eslot = edge within this group's chunk (serves 4 nodes) ---
        float w0 = 0.f, w1 = 0.f, w2 = 0.f;
        int src = 0;
        if (c0 + eslot < deg_g) {
            uint4 p = payload[beg_g + c0 + eslot];
            w0 = exp2f(leaky(bf_lo(p.x)));
            w1 = exp2f(leaky(bf_hi(p.x)));
            w2 = exp2f(leaky(bf_lo(p.y)));
            pae0 += bf_hi(p.y);
            pae1 += bf_lo(p.z);
            pae2 += bf_hi(p.z);
            pden0 += w0; pden1 += w1; pden2 += w2;
            src = (int)p.w;
        }
        wbuf[wid][lane] = make_float4(w0, w1, w2, __int_as_float(src));
        // --- phase B: full wave gathers each group's chunk serially ---
        #pragma unroll
        for (int g = 0; g < 4; ++g) {
            int dg = __shfl(deg_g, g * 16, 64);
            int cn = min(dg - c0, 16);
            int i = 0;
            for (; i + 2 <= cn; i += 2) {
                float4 ta = wbuf[wid][g * 16 + i];
                float4 tb = wbuf[wid][g * 16 + i + 1];
                unsigned ia = __umul24((unsigned)__float_as_int(ta.w), 96u) + lane;
                unsigned ib = __umul24((unsigned)__float_as_int(tb.w), 96u) + lane;
                unsigned va = xs32[ia];
                unsigned vb = xs32[ib];
                float xa2 = bf2f(xsb[(ia << 1) + c128ml]);
                float xb2 = bf2f(xsb[(ib << 1) + c128ml]);
                aA0[g] += ta.x * bf_lo(va); aA1[g] += ta.y * bf_hi(va); aA2[g] += ta.z * xa2;
                aB0[g] += tb.x * bf_lo(vb); aB1[g] += tb.y * bf_hi(vb); aB2[g] += tb.z * xb2;
            }
            if (i < cn) {
                float4 ta = wbuf[wid][g * 16 + i];
                unsigned ia = __umul24((unsigned)__float_as_int(ta.w), 96u) + lane;
                unsigned va = xs32[ia];
                aA0[g] += ta.x * bf_lo(va);
                aA1[g] += ta.y * bf_hi(va);
                aA2[g] += ta.z * bf2f(xsb[(ia << 1) + c128ml]);
            }
        }
    }

    // reduce den/ae within each 16-lane group (4 steps, serves 4 nodes)
    #pragma unroll
    for (int o = 1; o < 16; o <<= 1) {
        pden0 += __shfl_xor(pden0, o, 64);
        pden1 += __shfl_xor(pden1, o, 64);
        pden2 += __shfl_xor(pden2, o, 64);
        pae0  += __shfl_xor(pae0, o, 64);
        pae1  += __shfl_xor(pae1, o, 64);
        pae2  += __shfl_xor(pae2, o, 64);
    }

    // self-loop scalars per group (redundant over 16 lanes; issue cost /4)
    float dc = fmaxf((float)deg_g, 1.0f);
    float inv_dc = __builtin_amdgcn_rcpf(dc);
    int nh = n_gc * HH;
    float sl0 = leaky(a_src[nh + 0] + a_dst[nh + 0] + pae0 * inv_dc);
    float sl1 = leaky(a_src[nh + 1] + a_dst[nh + 1] + pae1 * inv_dc);
    float sl2 = leaky(a_src[nh + 2] + a_dst[nh + 2] + pae2 * inv_dc);
    float e0 = exp2f(sl0), e1 = exp2f(sl1), e2 = exp2f(sl2);
    float r0 = __builtin_amdgcn_rcpf(pden0 + e0);
    float r1 = __builtin_amdgcn_rcpf(pden1 + e1);
    float r2 = __builtin_amdgcn_rcpf(pden2 + e2);

    // write OA: per group, broadcast scalars to the whole wave
    #pragma unroll
    for (int g = 0; g < 4; ++g) {
        int row = wid * 4 + g;
        int n2c = min(nb16 + row, N - 1);
        float e0g = __shfl(e0, g * 16, 64), e1g = __shfl(e1, g * 16, 64), e2g = __shfl(e2, g * 16, 64);
        float r0g = __shfl(r0, g * 16, 64), r1g = __shfl(r1, g * 16, 64), r2g = __shfl(r2, g * 16, 64);
        unsigned ian = __umul24((unsigned)n2c, 96u) + lane;
        unsigned van = xs32[ian];
        float xn2v = bf2f(xsb[(ian << 1) + c128ml]);
        OA[row * OAP +       lane] = f2bf((aA0[g] + aB0[g] + e0g * bf_lo(van)) * r0g);
        OA[row * OAP +  64 + lane] = f2bf((aA1[g] + aB1[g] + e1g * bf_hi(van)) * r1g);
        OA[row * OAP + 128 + lane] = f2bf((aA2[g] + aB2[g] + e2g * xn2v) * r2g);
    }
    __syncthreads();

    // ======== MLP phase: wave wid owns output cols wid*16..wid*16+15 ========
    int l15 = lane & 15, kg = (lane >> 4) * 8;
    int col = wid * 16 + l15;
    float cb1 = b1p[col], cg1 = g1[col], cbe1 = be1[col];
    float cb2 = b2[col],  cg2 = g2[col], cbe2 = be2[col];

    // GEMM1: [16 x 192] @ [192 x 16(cols of this wave)]
    f32x4 acc = (f32x4){0.f, 0.f, 0.f, 0.f};
    #pragma unroll
    for (int k0 = 0; k0 < HC; k0 += 32) {
        bf16x8 af = *(const bf16x8*)&OA[l15 * OAP + k0 + kg];
        bf16x8 bf = *(const bf16x8*)(w1t + (size_t)col * HC + k0 + kg);
        acc = __builtin_amdgcn_mfma_f32_16x16x32_bf16(af, bf, acc, 0, 0, 0);
    }

    int rj0 = (lane >> 4) * 4;
    float y[4], h1v[4];
    #pragma unroll
    for (int j = 0; j < 4; ++j) {
        int r = min(nb16 + rj0 + j, N - 1);
        y[j] = acc[j] + cb1 + x[(size_t)r * DIN + col];
        float s = y[j], q = y[j] * y[j];
        #pragma unroll
        for (int o = 1; o < 16; o <<= 1) {
            s += __shfl_xor(s, o, 64);
            q += __shfl_xor(q, o, 64);
        }
        if (l15 == 0) { red[0][wid][rj0 + j] = s; red[1][wid][rj0 + j] = q; }
    }
    __syncthreads();
    #pragma unroll
    for (int j = 0; j < 4; ++j) {
        int rj = rj0 + j;
        float s = red[0][0][rj] + red[0][1][rj] + red[0][2][rj] + red[0][3][rj];
        float q = red[1][0][rj] + red[1][1][rj] + red[1][2][rj] + red[1][3][rj];
        float m = s * (1.0f / CC);
        float var = q * (1.0f / CC) - m * m;
        float inv = rsqrtf(var + LN_EPS);
        float h = (y[j] - m) * inv * cg1 + cbe1;
        h1v[j] = h;
        H1s[rj * 72 + col] = f2bf(h);
    }
    __syncthreads();

    // GEMM2: [16 x 64] @ [64 x 16]
    f32x4 acc2 = (f32x4){0.f, 0.f, 0.f, 0.f};
    #pragma unroll
    for (int k0 = 0; k0 < CC; k0 += 32) {
        bf16x8 af = *(const bf16x8*)&H1s[l15 * 72 + k0 + kg];
        bf16x8 bf = *(const bf16x8*)(w2t + (size_t)col * CC + k0 + kg);
        acc2 = __builtin_amdgcn_mfma_f32_16x16x32_bf16(af, bf, acc2, 0, 0, 0);
    }

    float z[4];
    #pragma unroll
    for (int j = 0; j < 4; ++j) {
        z[j] = acc2[j] + cb2 + h1v[j];
        float s = z[j], q = z[j] * z[j];
        #pragma unroll
        for (int o = 1; o < 16; o <<= 1) {
            s += __shfl_xor(s, o, 64);
            q += __shfl_xor(q, o, 64);
        }
        if (l15 == 0) { red[0][wid][rj0 + j] = s; red[1][wid][rj0 + j] = q; }
    }
    __syncthreads();
    #pragma unroll
    for (int j = 0; j < 4; ++j) {
        int rj = rj0 + j;
        float s = red[0][0][rj] + red[0][1][rj] + red[0][2][rj] + red[0][3][rj];
        float q = red[1][0][rj] + red[1][1][rj] + red[1][2][rj] + red[1][3][rj];
        float m = s * (1.0f / CC);
        float var = q * (1.0f / CC) - m * m;
        float inv = rsqrtf(var + LN_EPS);
        int r = nb16 + rj;
        if (r < N)
            out[(size_t)r * CC + col] = (z[j] - m) * inv * cg2 + cbe2;
    }
}

extern "C" void kernel_launch(void* const* d_in, const int* in_sizes, int n_in,
                              void* d_out, int out_size, void* d_ws, size_t ws_size,
                              hipStream_t stream) {
    const float* x          = (const float*)d_in[0];
    const float* edge_attr  = (const float*)d_in[1];
    const float* lin_w      = (const float*)d_in[2];
    const float* att_src    = (const float*)d_in[3];
    const float* att_dst    = (const float*)d_in[4];
    const float* lin_edge_w = (const float*)d_in[5];
    const float* att_edge   = (const float*)d_in[6];
    const float* gat_bias   = (const float*)d_in[7];
    const float* w1         = (const float*)d_in[8];
    const float* b1         = (const float*)d_in[9];
    const float* ln1_g      = (const float*)d_in[10];
    const float* ln1_b      = (const float*)d_in[11];
    const float* w2         = (const float*)d_in[12];
    const float* b2         = (const float*)d_in[13];
    const float* ln2_g      = (const float*)d_in[14];
    const float* ln2_b      = (const float*)d_in[15];
    const int*   ei         = (const int*)d_in[16];
    float* out = (float*)d_out;

    const int N = in_sizes[0] / DIN;
    const int E = in_sizes[1] / ED;
    const int nb_scan = (N + 255) / 256;
    const int nbx = (N + 63) / 64;

    char* ws = (char*)d_ws;
    size_t off_b = 0;
    auto alloc = [&](size_t bytes) {
        size_t o = off_b;
        off_b = (off_b + bytes + 255) & ~(size_t)255;
        return o;
    };
    // zeroed region first (single memset)
    int* icnt = (int*)(ws + alloc((size_t)N * 4));
    int* gtot = (int*)(ws + alloc(4));
    size_t zero_bytes = off_b;
    // fully-overwritten region
    unsigned short* xsb = (unsigned short*)(ws + alloc((size_t)N * HC * 2));
    float*  a_srcb  = (float*)(ws + alloc((size_t)N * HH * 4));
    float*  a_dstb  = (float*)(ws + alloc((size_t)N * HH * 4));
    int*    offb    = (int*)(ws + alloc((size_t)N * 4));
    int*    cursor  = (int*)(ws + alloc((size_t)N * 4));
    uint4*  payload = (uint4*)(ws + alloc((size_t)E * 16));
    unsigned short* linwt = (unsigned short*)(ws + alloc((size_t)HC * DIN * 2));
    unsigned short* w1t   = (unsigned short*)(ws + alloc((size_t)DIN * HC * 2));
    unsigned short* w2t   = (unsigned short*)(ws + alloc((size_t)CC * CC * 2));
    float* b1p = (float*)(ws + alloc((size_t)CC * 4));
    float* we  = (float*)(ws + alloc((size_t)ED * HH * 4));
    (void)ws_size; (void)n_in; (void)out_size;

    hipMemsetAsync(d_ws, 0, zero_bytes, stream);

    k_prep_cnt<<<PREP_BLOCKS + (E + 255) / 256, 256, 0, stream>>>(
        lin_w, w1, w2, b1, gat_bias, lin_edge_w, att_edge,
        linwt, w1t, w2t, b1p, we, ei, icnt, E);
    k_xs<<<nbx + nb_scan, 256, 0, stream>>>(x, linwt, att_src, att_dst, xsb,
                                            a_srcb, a_dstb, icnt, gtot, offb, cursor,
                                            N, nbx);
    k_fill<<<(E + 255) / 256, 256, 0, stream>>>(edge_attr, ei, a_srcb, a_dstb, we, cursor,
                                                payload, E);
    k_gatmlp<<<(N + 15) / 16, 256, 0, stream>>>(xsb, a_srcb, a_dstb, offb, icnt, payload,
                                                x, w1t, w2t, b1p, ln1_g, ln1_b,
                                                b2, ln2_g, ln2_b, out, N);
}

// Round 15
// 181.991 us; speedup vs baseline: 1.0338x; 1.0338x over previous
//
#include <hip/hip_runtime.h>

// GraphTransformerBlock2: GATConv(H=3,C=64, edge_dim=5, self-loops w/ mean fill)
// -> linear1 -> LN(x + .) -> linear2 -> LN(lin + .)
// All float32 I/O. edge_index int32 (2,E): src=ei[0:E], dst=ei[E:2E].
//
// R14: revert gather to R12's 1-node/wave body (R13's 4-node packing lost to
//      max-degree load imbalance + short-loop overhead). Keep OA stride 200
//      (R12's 16-way GEMM1 bank conflict -> conflict-optimal).
//      k_prep: b1p/we serial single-wave loops parallelized (coalesced
//      k-chunk partials + LDS reduce) - they were dispatch-critical-path.

#define HH 3
#define CC 64
#define DIN 64
#define ED 5
#define HC 192
#define OAP 200                 // padded OA row stride (u16): 100 dwords == 4 mod 32
#define NEG_SLOPE 0.2f
#define LN_EPS 1e-5f
#define LOG2E 1.44269504f

typedef __attribute__((ext_vector_type(8))) short bf16x8;
typedef __attribute__((ext_vector_type(4))) float f32x4;

__device__ __forceinline__ float leaky(float l) { return fmaxf(l, NEG_SLOPE * l); }

__device__ __forceinline__ unsigned short f2bf(float f) {
    unsigned u = __float_as_uint(f);
    unsigned r = (u + 0x7FFFu + ((u >> 16) & 1u)) >> 16;   // RNE
    return (unsigned short)r;
}
__device__ __forceinline__ float bf2f(unsigned short u) {
    return __uint_as_float((unsigned)u << 16);
}
__device__ __forceinline__ float bf_lo(unsigned v) { return __uint_as_float(v << 16); }
__device__ __forceinline__ float bf_hi(unsigned v) { return __uint_as_float(v & 0xFFFF0000u); }

__device__ __forceinline__ bf16x8 pack8(float4 a, float4 b) {
    bf16x8 r;
    r[0] = (short)f2bf(a.x); r[1] = (short)f2bf(a.y);
    r[2] = (short)f2bf(a.z); r[3] = (short)f2bf(a.w);
    r[4] = (short)f2bf(b.x); r[5] = (short)f2bf(b.y);
    r[6] = (short)f2bf(b.z); r[7] = (short)f2bf(b.w);
    return r;
}

// ---------- prep: transposes (blocks 0..27), b1p+we (block 28), cnt (rest) ----------
#define PREP_TRANS (HC*DIN + DIN*HC + CC*CC)
#define PREP_BLOCKS 28
__global__ __launch_bounds__(256) void k_prep_cnt(const float* __restrict__ lin_w,
                                                  const float* __restrict__ w1,
                                                  const float* __restrict__ w2,
                                                  const float* __restrict__ b1,
                                                  const float* __restrict__ gat_bias,
                                                  const float* __restrict__ lin_edge_w,
                                                  const float* __restrict__ att_edge,
                                                  unsigned short* __restrict__ linwt,
                                                  unsigned short* __restrict__ w1t,
                                                  unsigned short* __restrict__ w2t,
                                                  float* __restrict__ b1p,
                                                  float* __restrict__ we,
                                                  const int* __restrict__ ei,
                                                  int* __restrict__ icnt, int E) {
    if (blockIdx.x < PREP_BLOCKS) {
        for (int i = blockIdx.x * 256 + threadIdx.x; i < PREP_TRANS; i += PREP_BLOCKS * 256) {
            if (i < HC * DIN) {
                int c = i >> 6, k = i & 63;
                linwt[i] = f2bf(lin_w[k * HC + c]);
            } else if (i < 2 * HC * DIN) {
                int j = i - HC * DIN;
                int c = j / HC, k = j - c * HC;
                w1t[j] = f2bf(w1[k * CC + c]);
            } else {
                int j = i - 2 * HC * DIN;
                int c = j >> 6, k = j & 63;
                w2t[j] = f2bf(w2[k * CC + c]);
            }
        }
    } else if (blockIdx.x == PREP_BLOCKS) {
        // b1p[c] = b1[c] + sum_k gat_bias[k]*w1[k*CC+c]  (4 k-chunks, coalesced)
        __shared__ float pb[4][CC];
        __shared__ float pw[15][16];
        int t = threadIdx.x;
        int c = t & 63, kq = t >> 6;
        float s = 0.f;
        for (int k = kq * 48; k < kq * 48 + 48; ++k)
            s += gat_bias[k] * w1[k * CC + c];
        pb[kq][c] = s;
        // we[q=d*HH+h] = LOG2E * sum_c lin_edge_w[d*HC+h*CC+c]*att_edge[h*CC+c]
        int q = t >> 4, cq = t & 15;
        if (q < 15) {
            int d = q / HH, h = q - d * HH;
            float s2 = 0.f;
            #pragma unroll
            for (int c2 = cq * 4; c2 < cq * 4 + 4; ++c2)
                s2 += lin_edge_w[d * HC + h * CC + c2] * att_edge[h * CC + c2];
            pw[q][cq] = s2;
        }
        __syncthreads();
        if (t < CC) b1p[t] = b1[t] + pb[0][t] + pb[1][t] + pb[2][t] + pb[3][t];
        if (t < 15) {
            float tot = 0.f;
            #pragma unroll
            for (int i2 = 0; i2 < 16; ++i2) tot += pw[t][i2];
            we[t] = tot * LOG2E;
        }
    } else {
        int nb = gridDim.x - PREP_BLOCKS - 1;
        for (int e = (blockIdx.x - PREP_BLOCKS - 1) * 256 + threadIdx.x; e < E; e += nb * 256)
            atomicAdd(&icnt[ei[E + e]], 1);
    }
}

// ---------- xs = x @ lin_w (MFMA) -> packed xsb + a_src/a_dst;  scan fused ----------
__global__ __launch_bounds__(256) void k_xs(const float* __restrict__ x,
                                            const unsigned short* __restrict__ linwt,
                                            const float* __restrict__ att_src,
                                            const float* __restrict__ att_dst,
                                            unsigned short* __restrict__ xsb,
                                            float* __restrict__ a_src,
                                            float* __restrict__ a_dst,
                                            const int* __restrict__ icnt,
                                            int* __restrict__ gtot,
                                            int* __restrict__ off,
                                            int* __restrict__ cursor,
                                            int N, int nbx) {
    __shared__ int wt[4];
    __shared__ int base_sh;
    if ((int)blockIdx.x >= nbx) {
        int bid = blockIdx.x - nbx;
        int i = bid * 256 + threadIdx.x;
        int lane = threadIdx.x & 63, wid = threadIdx.x >> 6;
        int v = (i < N) ? icnt[i] : 0;
        int incl = v;
        #pragma unroll
        for (int o = 1; o < 64; o <<= 1) {
            int u = __shfl_up(incl, o, 64);
            if (lane >= o) incl += u;
        }
        if (lane == 63) wt[wid] = incl;
        __syncthreads();
        if (threadIdx.x == 0)
            base_sh = atomicAdd(gtot, wt[0] + wt[1] + wt[2] + wt[3]);
        __syncthreads();
        int wpre = 0;
        for (int w2 = 0; w2 < wid; ++w2) wpre += wt[w2];
        int excl = base_sh + wpre + incl - v;
        if (i < N) { off[i] = excl; cursor[i] = excl; }
        return;
    }

    int lane = threadIdx.x & 63, w = threadIdx.x >> 6;
    int l15 = lane & 15, kg = (lane >> 4) * 8;
    int nb = blockIdx.x * 64;
    int arow = nb + w * 16 + l15;
    int arow_c = min(arow, N - 1);

    f32x4 acc[12];
    #pragma unroll
    for (int ct = 0; ct < 12; ++ct) acc[ct] = (f32x4){0.f, 0.f, 0.f, 0.f};

    #pragma unroll
    for (int k0 = 0; k0 < DIN; k0 += 32) {
        const float* ap = x + (size_t)arow_c * DIN + k0 + kg;
        float4 a0 = *(const float4*)ap;
        float4 a1 = *(const float4*)(ap + 4);
        bf16x8 af = pack8(a0, a1);
        #pragma unroll
        for (int ct = 0; ct < 12; ++ct) {
            bf16x8 bf = *(const bf16x8*)(linwt + (size_t)(ct * 16 + l15) * DIN + k0 + kg);
            acc[ct] = __builtin_amdgcn_mfma_f32_16x16x32_bf16(af, bf, acc[ct], 0, 0, 0);
        }
    }

    float asv[12], adv[12];
    #pragma unroll
    for (int ct = 0; ct < 12; ++ct) {
        int c = ct * 16 + l15;
        asv[ct] = att_src[c]; adv[ct] = att_dst[c];
    }

    int rbase = nb + w * 16 + (lane >> 4) * 4;
    #pragma unroll
    for (int j = 0; j < 4; ++j) {
        int r = rbase + j;
        bool ok = r < N;
        float ps0 = 0.f, ps1 = 0.f, ps2 = 0.f, pd0 = 0.f, pd1 = 0.f, pd2 = 0.f;
        #pragma unroll
        for (int ct = 0; ct < 12; ++ct) {
            float v = acc[ct][j];
            float s = v * asv[ct], d = v * adv[ct];
            if (ct < 4)      { ps0 += s; pd0 += d; }
            else if (ct < 8) { ps1 += s; pd1 += d; }
            else             { ps2 += s; pd2 += d; }
        }
        if (ok) {
            unsigned* row32 = (unsigned*)(xsb + (size_t)r * HC);
            #pragma unroll
            for (int ct = 0; ct < 4; ++ct) {
                int c = ct * 16 + l15;
                row32[c] = (unsigned)f2bf(acc[ct][j]) | ((unsigned)f2bf(acc[ct + 4][j]) << 16);
                xsb[(size_t)r * HC + 128 + c] = f2bf(acc[ct + 8][j]);
            }
        }
        #pragma unroll
        for (int o = 1; o < 16; o <<= 1) {
            ps0 += __shfl_xor(ps0, o, 64); pd0 += __shfl_xor(pd0, o, 64);
            ps1 += __shfl_xor(ps1, o, 64); pd1 += __shfl_xor(pd1, o, 64);
            ps2 += __shfl_xor(ps2, o, 64); pd2 += __shfl_xor(pd2, o, 64);
        }
        if (ok && l15 == 0) {
            a_src[r * HH + 0] = ps0 * LOG2E; a_src[r * HH + 1] = ps1 * LOG2E;
            a_src[r * HH + 2] = ps2 * LOG2E;
            a_dst[r * HH + 0] = pd0 * LOG2E; a_dst[r * HH + 1] = pd1 * LOG2E;
            a_dst[r * HH + 2] = pd2 * LOG2E;
        }
    }
}

// ---------- payload fill (CSR order), 16B/edge, a_dst FOLDED IN ----------
__global__ __launch_bounds__(256) void k_fill(const float* __restrict__ ea,
                                              const int* __restrict__ ei,
                                              const float* __restrict__ a_src,
                                              const float* __restrict__ a_dst,
                                              const float* __restrict__ we,
                                              int* __restrict__ cursor,
                                              uint4* __restrict__ payload, int E) {
    int e = blockIdx.x * blockDim.x + threadIdx.x;
    if (e >= E) return;
    int s = ei[e], d = ei[E + e];
    int pos = atomicAdd(&cursor[d], 1);                  // issue early; hide RMW latency
    float attr[ED];
    #pragma unroll
    for (int j = 0; j < ED; ++j) attr[j] = ea[(size_t)e * ED + j];
    float aeh[HH], lp[HH];
    #pragma unroll
    for (int h = 0; h < HH; ++h) {
        float a = 0.f;
        #pragma unroll
        for (int j = 0; j < ED; ++j) a += attr[j] * we[j * HH + h];   // we pre-scaled
        aeh[h] = a;
        lp[h] = a_src[s * HH + h] + a_dst[d * HH + h] + a;             // all pre-scaled
    }
    uint4 pk;
    pk.x = (unsigned)f2bf(lp[0])  | ((unsigned)f2bf(lp[1])  << 16);
    pk.y = (unsigned)f2bf(lp[2])  | ((unsigned)f2bf(aeh[0]) << 16);
    pk.z = (unsigned)f2bf(aeh[1]) | ((unsigned)f2bf(aeh[2]) << 16);
    pk.w = (unsigned)s;
    payload[pos] = pk;
}

// ---------- FUSED: per-dst softmax+gather (16-node tile) -> MLP -> out ----------
__global__ __launch_bounds__(256) void k_gatmlp(const unsigned short* __restrict__ xsb,
                                                const float* __restrict__ a_src,
                                                const float* __restrict__ a_dst,
                                                const int* __restrict__ off,
                                                const int* __restrict__ icnt,
                                                const uint4* __restrict__ payload,
                                                const float* __restrict__ x,
                                                const unsigned short* __restrict__ w1t,
                                                const unsigned short* __restrict__ w2t,
                                                const float* __restrict__ b1p,
                                                const float* __restrict__ g1,
                                                const float* __restrict__ be1,
                                                const float* __restrict__ b2,
                                                const float* __restrict__ g2,
                                                const float* __restrict__ be2,
                                                float* __restrict__ out, int N) {
    __shared__ float4 wbuf[4][64];                 // 4 KB
    __shared__ unsigned short OA[16 * OAP];        // 6.25 KB, padded stride
    __shared__ unsigned short H1s[16 * 72];        // 2.25 KB
    __shared__ float red[2][4][16];                // 512 B
    int lane = threadIdx.x & 63;
    int wid  = threadIdx.x >> 6;
    const unsigned* xs32 = (const unsigned*)xsb;
    unsigned c128ml = 128u - (unsigned)lane;
    int nb16 = blockIdx.x * 16;

    // ======== gather phase: each wave handles 4 nodes serially ========
    #pragma unroll 1
    for (int t = 0; t < 4; ++t) {
        int row = wid * 4 + t;
        int n = nb16 + row;
        if (n < N) {
            int beg = off[n];
            int deg = icnt[n];
            float pden0 = 0.f, pden1 = 0.f, pden2 = 0.f;
            float pae0 = 0.f, pae1 = 0.f, pae2 = 0.f;
            float a0A = 0.f, a1A = 0.f, a2A = 0.f;
            float a0B = 0.f, a1B = 0.f, a2B = 0.f;

            for (int c0 = 0; c0 < deg; c0 += 64) {
                int cn = min(deg - c0, 64);
                float w0 = 0.f, w1 = 0.f, w2 = 0.f;
                int src = 0;
                if (lane < cn) {
                    uint4 p = payload[beg + c0 + lane];
                    w0 = exp2f(leaky(bf_lo(p.x)));
                    w1 = exp2f(leaky(bf_hi(p.x)));
                    w2 = exp2f(leaky(bf_lo(p.y)));
                    pae0 += bf_hi(p.y);
                    pae1 += bf_lo(p.z);
                    pae2 += bf_hi(p.z);
                    pden0 += w0; pden1 += w1; pden2 += w2;
                    src = (int)p.w;
                }
                wbuf[wid][lane] = make_float4(w0, w1, w2, __int_as_float(src));
                int i = 0;
                for (; i + 2 <= cn; i += 2) {
                    float4 ta = wbuf[wid][i];
                    float4 tb = wbuf[wid][i + 1];
                    unsigned ia = __umul24((unsigned)__float_as_int(ta.w), 96u) + lane;
                    unsigned ib = __umul24((unsigned)__float_as_int(tb.w), 96u) + lane;
                    unsigned va = xs32[ia];
                    unsigned vb = xs32[ib];
                    float xa2 = bf2f(xsb[(ia << 1) + c128ml]);
                    float xb2 = bf2f(xsb[(ib << 1) + c128ml]);
                    a0A += ta.x * bf_lo(va); a1A += ta.y * bf_hi(va); a2A += ta.z * xa2;
                    a0B += tb.x * bf_lo(vb); a1B += tb.y * bf_hi(vb); a2B += tb.z * xb2;
                }
                if (i < cn) {
                    float4 ta = wbuf[wid][i];
                    unsigned ia = __umul24((unsigned)__float_as_int(ta.w), 96u) + lane;
                    unsigned va = xs32[ia];
                    a0A += ta.x * bf_lo(va);
                    a1A += ta.y * bf_hi(va);
                    a2A += ta.z * bf2f(xsb[(ia << 1) + c128ml]);
                }
            }

            #pragma unroll
            for (int o = 32; o; o >>= 1) {
                pden0 += __shfl_xor(pden0, o, 64);
                pden1 += __shfl_xor(pden1, o, 64);
                pden2 += __shfl_xor(pden2, o, 64);
                pae0  += __shfl_xor(pae0, o, 64);
                pae1  += __shfl_xor(pae1, o, 64);
                pae2  += __shfl_xor(pae2, o, 64);
            }

            float dc = fmaxf((float)deg, 1.0f);
            float inv_dc = __builtin_amdgcn_rcpf(dc);
            float sl0 = leaky(a_src[n * HH + 0] + a_dst[n * HH + 0] + pae0 * inv_dc);
            float sl1 = leaky(a_src[n * HH + 1] + a_dst[n * HH + 1] + pae1 * inv_dc);
            float sl2 = leaky(a_src[n * HH + 2] + a_dst[n * HH + 2] + pae2 * inv_dc);
            float e0 = exp2f(sl0), e1 = exp2f(sl1), e2 = exp2f(sl2);
            unsigned ian = __umul24((unsigned)n, 96u) + lane;
            unsigned van = xs32[ian];
            float xn2 = bf2f(xsb[(ian << 1) + c128ml]);
            float r0 = __builtin_amdgcn_rcpf(pden0 + e0);
            float r1 = __builtin_amdgcn_rcpf(pden1 + e1);
            float r2 = __builtin_amdgcn_rcpf(pden2 + e2);
            OA[row * OAP +       lane] = f2bf((a0A + a0B + e0 * bf_lo(van)) * r0);
            OA[row * OAP +  64 + lane] = f2bf((a1A + a1B + e1 * bf_hi(van)) * r1);
            OA[row * OAP + 128 + lane] = f2bf((a2A + a2B + e2 * xn2) * r2);
        } else {
            OA[row * OAP +       lane] = 0;
            OA[row * OAP +  64 + lane] = 0;
            OA[row * OAP + 128 + lane] = 0;
        }
    }
    __syncthreads();

    // ======== MLP phase: wave wid owns output cols wid*16..wid*16+15 ========
    int l15 = lane & 15, kg = (lane >> 4) * 8;
    int col = wid * 16 + l15;
    float cb1 = b1p[col], cg1 = g1[col], cbe1 = be1[col];
    float cb2 = b2[col],  cg2 = g2[col], cbe2 = be2[col];

    // GEMM1: [16 x 192] @ [192 x 16(cols of this wave)]
    f32x4 acc = (f32x4){0.f, 0.f, 0.f, 0.f};
    #pragma unroll
    for (int k0 = 0; k0 < HC; k0 += 32) {
        bf16x8 af = *(const bf16x8*)&OA[l15 * OAP + k0 + kg];
        bf16x8 bf = *(const bf16x8*)(w1t + (size_t)col * HC + k0 + kg);
        acc = __builtin_amdgcn_mfma_f32_16x16x32_bf16(af, bf, acc, 0, 0, 0);
    }

    int rj0 = (lane >> 4) * 4;
    float y[4], h1v[4];
    #pragma unroll
    for (int j = 0; j < 4; ++j) {
        int r = min(nb16 + rj0 + j, N - 1);
        y[j] = acc[j] + cb1 + x[(size_t)r * DIN + col];
        float s = y[j], q = y[j] * y[j];
        #pragma unroll
        for (int o = 1; o < 16; o <<= 1) {
            s += __shfl_xor(s, o, 64);
            q += __shfl_xor(q, o, 64);
        }
        if (l15 == 0) { red[0][wid][rj0 + j] = s; red[1][wid][rj0 + j] = q; }
    }
    __syncthreads();
    #pragma unroll
    for (int j = 0; j < 4; ++j) {
        int rj = rj0 + j;
        float s = red[0][0][rj] + red[0][1][rj] + red[0][2][rj] + red[0][3][rj];
        float q = red[1][0][rj] + red[1][1][rj] + red[1][2][rj] + red[1][3][rj];
        float m = s * (1.0f / CC);
        float var = q * (1.0f / CC) - m * m;
        float inv = rsqrtf(var + LN_EPS);
        float h = (y[j] - m) * inv * cg1 + cbe1;
        h1v[j] = h;
        H1s[rj * 72 + col] = f2bf(h);
    }
    __syncthreads();

    // GEMM2: [16 x 64] @ [64 x 16]
    f32x4 acc2 = (f32x4){0.f, 0.f, 0.f, 0.f};
    #pragma unroll
    for (int k0 = 0; k0 < CC; k0 += 32) {
        bf16x8 af = *(const bf16x8*)&H1s[l15 * 72 + k0 + kg];
        bf16x8 bf = *(const bf16x8*)(w2t + (size_t)col * CC + k0 + kg);
        acc2 = __builtin_amdgcn_mfma_f32_16x16x32_bf16(af, bf, acc2, 0, 0, 0);
    }

    float z[4];
    #pragma unroll
    for (int j = 0; j < 4; ++j) {
        z[j] = acc2[j] + cb2 + h1v[j];
        float s = z[j], q = z[j] * z[j];
        #pragma unroll
        for (int o = 1; o < 16; o <<= 1) {
            s += __shfl_xor(s, o, 64);
            q += __shfl_xor(q, o, 64);
        }
        if (l15 == 0) { red[0][wid][rj0 + j] = s; red[1][wid][rj0 + j] = q; }
    }
    __syncthreads();
    #pragma unroll
    for (int j = 0; j < 4; ++j) {
        int rj = rj0 + j;
        float s = red[0][0][rj] + red[0][1][rj] + red[0][2][rj] + red[0][3][rj];
        float q = red[1][0][rj] + red[1][1][rj] + red[1][2][rj] + red[1][3][rj];
        float m = s * (1.0f / CC);
        float var = q * (1.0f / CC) - m * m;
        float inv = rsqrtf(var + LN_EPS);
        int r = nb16 + rj;
        if (r < N)
            out[(size_t)r * CC + col] = (z[j] - m) * inv * cg2 + cbe2;
    }
}

extern "C" void kernel_launch(void* const* d_in, const int* in_sizes, int n_in,
                              void* d_out, int out_size, void* d_ws, size_t ws_size,
                              hipStream_t stream) {
    const float* x          = (const float*)d_in[0];
    const float* edge_attr  = (const float*)d_in[1];
    const float* lin_w      = (const float*)d_in[2];
    const float* att_src    = (const float*)d_in[3];
    const float* att_dst    = (const float*)d_in[4];
    const float* lin_edge_w = (const float*)d_in[5];
    const float* att_edge   = (const float*)d_in[6];
    const float* gat_bias   = (const float*)d_in[7];
    const float* w1         = (const float*)d_in[8];
    const float* b1         = (const float*)d_in[9];
    const float* ln1_g      = (const float*)d_in[10];
    const float* ln1_b      = (const float*)d_in[11];
    const float* w2         = (const float*)d_in[12];
    const float* b2         = (const float*)d_in[13];
    const float* ln2_g      = (const float*)d_in[14];
    const float* ln2_b      = (const float*)d_in[15];
    const int*   ei         = (const int*)d_in[16];
    float* out = (float*)d_out;

    const int N = in_sizes[0] / DIN;
    const int E = in_sizes[1] / ED;
    const int nb_scan = (N + 255) / 256;
    const int nbx = (N + 63) / 64;

    char* ws = (char*)d_ws;
    size_t off_b = 0;
    auto alloc = [&](size_t bytes) {
        size_t o = off_b;
        off_b = (off_b + bytes + 255) & ~(size_t)255;
        return o;
    };
    // zeroed region first (single memset)
    int* icnt = (int*)(ws + alloc((size_t)N * 4));
    int* gtot = (int*)(ws + alloc(4));
    size_t zero_bytes = off_b;
    // fully-overwritten region
    unsigned short* xsb = (unsigned short*)(ws + alloc((size_t)N * HC * 2));
    float*  a_srcb  = (float*)(ws + alloc((size_t)N * HH * 4));
    float*  a_dstb  = (float*)(ws + alloc((size_t)N * HH * 4));
    int*    offb    = (int*)(ws + alloc((size_t)N * 4));
    int*    cursor  = (int*)(ws + alloc((size_t)N * 4));
    uint4*  payload = (uint4*)(ws + alloc((size_t)E * 16));
    unsigned short* linwt = (unsigned short*)(ws + alloc((size_t)HC * DIN * 2));
    unsigned short* w1t   = (unsigned short*)(ws + alloc((size_t)DIN * HC * 2));
    unsigned short* w2t   = (unsigned short*)(ws + alloc((size_t)CC * CC * 2));
    float* b1p = (float*)(ws + alloc((size_t)CC * 4));
    float* we  = (float*)(ws + alloc((size_t)ED * HH * 4));
    (void)ws_size; (void)n_in; (void)out_size;

    hipMemsetAsync(d_ws, 0, zero_bytes, stream);

    k_prep_cnt<<<PREP_BLOCKS + 1 + (E + 255) / 256, 256, 0, stream>>>(
        lin_w, w1, w2, b1, gat_bias, lin_edge_w, att_edge,
        linwt, w1t, w2t, b1p, we, ei, icnt, E);
    k_xs<<<nbx + nb_scan, 256, 0, stream>>>(x, linwt, att_src, att_dst, xsb,
                                            a_srcb, a_dstb, icnt, gtot, offb, cursor,
                                            N, nbx);
    k_fill<<<(E + 255) / 256, 256, 0, stream>>>(edge_attr, ei, a_srcb, a_dstb, we, cursor,
                                                payload, E);
    k_gatmlp<<<(N + 15) / 16, 256, 0, stream>>>(xsb, a_srcb, a_dstb, offb, icnt, payload,
                                                x, w1t, w2t, b1p, ln1_g, ln1_b,
                                                b2, ln2_g, ln2_b, out, N);
}